// Round 2
// baseline (267.932 us; speedup 1.0000x reference)
//
#include <hip/hip_runtime.h>

#define S_LEN 8192
#define DI 256
#define NS 8
#define CHUNK 64
#define NCH 128   // S_LEN / CHUNK
#define PT 32     // positions per prep block
#define FT 16     // rows per out-GEMM block

__device__ __forceinline__ float silu_f(float v){ return v / (1.f + __expf(-v)); }

// ---------------------------------------------------------------- K1: fold output projections
// Ms[d][m] = sum_{e<64} Ws[e][d]*Wo[m][e];  Mt[d][m] = sum_e Wt[e][d]*Wo[m][64+e];
// Mc[ch][m] = Wo[m][128+ch]
__global__ __launch_bounds__(256) void k_foldw(
    const float* __restrict__ Ws, const float* __restrict__ Wt, const float* __restrict__ Wo,
    float* __restrict__ Ms, float* __restrict__ Mt, float* __restrict__ Mc)
{
  const int d = blockIdx.x;
  const int m = threadIdx.x;
  float as = 0.f, at = 0.f;
  for(int e = 0; e < 64; ++e){
    as += Ws[e*DI + d] * Wo[m*DI + e];
    at += Wt[e*DI + d] * Wo[m*DI + 64 + e];
  }
  Ms[d*DI + m] = as;
  Mt[d*DI + m] = at;
  if(d < 128) Mc[d*DI + m] = Wo[m*DI + 128 + d];
}

// ---------------------------------------------------------------- K2: in_proj GEMM
// xi[s][d] = sum_c x[s][c] * Wp[d][c]
#define K2_ROWS 16
__global__ __launch_bounds__(256) void k_inproj(
    const float* __restrict__ x, const float* __restrict__ Wp, float* __restrict__ xi)
{
  __shared__ float xl[K2_ROWS][DI];
  const int s0 = blockIdx.x * K2_ROWS;
  const int tid = threadIdx.x;
  for(int i = tid; i < K2_ROWS*DI/4; i += 256){
    int r = i >> 6, c = (i & 63) << 2;
    float4 v = *reinterpret_cast<const float4*>(x + (size_t)(s0 + r)*DI + c);
    xl[r][c] = v.x; xl[r][c+1] = v.y; xl[r][c+2] = v.z; xl[r][c+3] = v.w;
  }
  __syncthreads();
  const int d = tid;
  float acc[K2_ROWS];
  #pragma unroll
  for(int r = 0; r < K2_ROWS; ++r) acc[r] = 0.f;
  const float* wrow = Wp + (size_t)d * DI;
  for(int c = 0; c < DI; c += 4){
    float4 wv = *reinterpret_cast<const float4*>(wrow + c);
    #pragma unroll
    for(int r = 0; r < K2_ROWS; ++r)
      acc[r] += wv.x*xl[r][c] + wv.y*xl[r][c+1] + wv.z*xl[r][c+2] + wv.w*xl[r][c+3];
  }
  #pragma unroll
  for(int r = 0; r < K2_ROWS; ++r)
    xi[(size_t)(s0 + r)*DI + d] = acc[r];
}

// ---------------------------------------------------------------- K3: gather time-order rows
// xi_t[p][d] = xi_s[s(p)][d],  s(p) = (p&7)<<10 | (p>>3)
__global__ __launch_bounds__(256) void k_gather_t(
    const float* __restrict__ xi_s, float* __restrict__ xi_t)
{
  const int p0 = blockIdx.x * 16;
  const int d = threadIdx.x;
  for(int r = 0; r < 16; ++r){
    int p = p0 + r;
    int s = ((p & 7) << 10) | (p >> 3);
    xi_t[(size_t)p*DI + d] = xi_s[(size_t)s*DI + d];
  }
}

// ---------------------------------------------------------------- K4: per-branch prep
// xc = silu(dwconv(X)); dbl = xproj @ xc; delta = softplus(dtw@dtp + 2*dtb); store u, delta, B, C
__global__ __launch_bounds__(256) void k_prep(
    const float* __restrict__ xi_s, const float* __restrict__ xi_t,
    const float* __restrict__ cw_s, const float* __restrict__ cb_s,
    const float* __restrict__ xp_s, const float* __restrict__ dtw_s, const float* __restrict__ dtb_s,
    const float* __restrict__ cw_t, const float* __restrict__ cb_t,
    const float* __restrict__ xp_t, const float* __restrict__ dtw_t, const float* __restrict__ dtb_t,
    float* __restrict__ u_g, float* __restrict__ d_g,
    float* __restrict__ B_g, float* __restrict__ C_g)
{
  const int br = blockIdx.y;
  const float* X   = br ? xi_t  : xi_s;
  const float* cw  = br ? cw_t  : cw_s;
  const float* cb  = br ? cb_t  : cb_s;
  const float* xpw = br ? xp_t  : xp_s;
  const float* dtw = br ? dtw_t : dtw_s;
  const float* dtb = br ? dtb_t : dtb_s;
  float* ug = u_g + (size_t)br * S_LEN * DI;
  float* dg = d_g + (size_t)br * S_LEN * DI;
  float* Bg = B_g + (size_t)br * S_LEN * NS;
  float* Cg = C_g + (size_t)br * S_LEN * NS;

  __shared__ float xc[PT][DI + 1];
  __shared__ float dbl[32][PT + 1];

  const int tid = threadIdx.x;
  const int l0 = blockIdx.x * PT;

  { // phase A: depthwise conv + silu, thread = d
    const int d = tid;
    float w0 = cw[d*3], w1 = cw[d*3 + 1], w2 = cw[d*3 + 2];
    float bb = cb[d];
    float xm = (l0 > 0) ? X[(size_t)(l0 - 1)*DI + d] : 0.f;
    float x0 = X[(size_t)l0*DI + d];
    for(int pos = 0; pos < PT; ++pos){
      int l = l0 + pos;
      float xp = (l + 1 < S_LEN) ? X[(size_t)(l + 1)*DI + d] : 0.f;
      float v = w0*xm + w1*x0 + w2*xp + bb;
      float xcv = silu_f(v);
      ug[(size_t)l*DI + d] = xcv;
      xc[pos][d] = xcv;
      xm = x0; x0 = xp;
    }
  }
  __syncthreads();
  { // phase B: dbl[e][pos] = sum_d xpw[e][d]*xc[pos][d]; lanes = pos, 4 e's per thread
    const int pos = tid & 31;
    const int e0 = tid >> 5;   // 0..7
    float a0 = 0.f, a1 = 0.f, a2 = 0.f, a3 = 0.f;
    for(int d = 0; d < DI; ++d){
      float xv = xc[pos][d];
      a0 += xpw[(e0      )*DI + d] * xv;
      a1 += xpw[(e0 +  8 )*DI + d] * xv;
      a2 += xpw[(e0 + 16 )*DI + d] * xv;
      a3 += xpw[(e0 + 24 )*DI + d] * xv;
    }
    dbl[e0     ][pos] = a0;
    dbl[e0 +  8][pos] = a1;
    dbl[e0 + 16][pos] = a2;
    dbl[e0 + 24][pos] = a3;
  }
  __syncthreads();
  { // write B (rows 16..23) and C (rows 24..31)
    const int pos = tid >> 3;
    const int n = tid & 7;
    Bg[(size_t)(l0 + pos)*NS + n] = dbl[16 + n][pos];
    Cg[(size_t)(l0 + pos)*NS + n] = dbl[24 + n][pos];
  }
  { // phase C: delta = softplus(dtw @ dtp + 2*dtb), thread = d
    const int d = tid;
    float dw[16];
    #pragma unroll
    for(int r = 0; r < 16; ++r) dw[r] = dtw[d*16 + r];
    const float b2 = 2.f * dtb[d];
    for(int pos = 0; pos < PT; ++pos){
      float a = b2;
      #pragma unroll
      for(int r = 0; r < 16; ++r) a += dw[r] * dbl[r][pos];
      float dlt = (a > 15.f) ? a : log1pf(__expf(a));
      dg[(size_t)(l0 + pos)*DI + d] = dlt;
    }
  }
}

// ---------------------------------------------------------------- K5: grouped conv branch (cy)
// yc[s][ch] = silu(b[ch] + sum_k w[ch][0][k]*xi_s[s+k-1][2ch] + w[ch][1][k]*xi_s[s+k-1][2ch+1])
__global__ __launch_bounds__(256) void k_convbranch(
    const float* __restrict__ xi_s, const float* __restrict__ bw, const float* __restrict__ bb,
    float* __restrict__ yc)
{
  const int t = blockIdx.x * 256 + threadIdx.x;   // t < S_LEN*128
  const int ch = t & 127;
  const int s = t >> 7;
  float acc = bb[ch];
  #pragma unroll
  for(int k = 0; k < 3; ++k){
    int l = s + k - 1;
    if(l >= 0 && l < S_LEN){
      acc += bw[ch*6 + k]     * xi_s[(size_t)l*DI + 2*ch];
      acc += bw[ch*6 + 3 + k] * xi_s[(size_t)l*DI + 2*ch + 1];
    }
  }
  yc[t] = silu_f(acc);
}

// ---------------------------------------------------------------- K6: scan pass 1 (local chunk scans)
__global__ __launch_bounds__(256) void k_scan1(
    const float* __restrict__ d_g, const float* __restrict__ u_g,
    const float* __restrict__ B_g,
    const float* __restrict__ Al_s, const float* __restrict__ Al_t,
    float* __restrict__ Pa, float* __restrict__ Ph)
{
  const int br = blockIdx.y;
  const int c = blockIdx.x;
  const int d = threadIdx.x;
  const float* dg = d_g + (size_t)br * S_LEN * DI;
  const float* ug = u_g + (size_t)br * S_LEN * DI;
  const float* Bg = B_g + (size_t)br * S_LEN * NS;
  const float* Al = br ? Al_t : Al_s;
  __shared__ float Bl[CHUNK][NS];
  const int l0 = c * CHUNK;
  for(int i = threadIdx.x; i < CHUNK*NS; i += 256)
    ((float*)Bl)[i] = Bg[(size_t)l0*NS + i];
  __syncthreads();
  float A2[NS], h[NS], ap[NS];
  #pragma unroll
  for(int n = 0; n < NS; ++n){
    A2[n] = -__expf(Al[d*NS + n]) * 1.4426950408889634f;  // A * log2(e)
    h[n] = 0.f; ap[n] = 1.f;
  }
  for(int l = 0; l < CHUNK; ++l){
    float dl = dg[(size_t)(l0 + l)*DI + d];
    float du = dl * ug[(size_t)(l0 + l)*DI + d];
    #pragma unroll
    for(int n = 0; n < NS; ++n){
      float a = exp2f(dl * A2[n]);
      ap[n] *= a;
      h[n] = a*h[n] + du * Bl[l][n];
    }
  }
  size_t base = (((size_t)br*NCH + c)*DI + d) * NS;
  #pragma unroll
  for(int n = 0; n < NS; ++n){ Pa[base + n] = ap[n]; Ph[base + n] = h[n]; }
}

// ---------------------------------------------------------------- K7: scan pass 2 (chunk combine)
// In-place: Ph[c] becomes the INITIAL state for chunk c.
__global__ __launch_bounds__(256) void k_scan2(
    const float* __restrict__ Pa, float* __restrict__ Ph)
{
  const int t = blockIdx.x * 256 + threadIdx.x;  // 4096 total
  const int br = t >> 11;
  const int idx = t & 2047;                      // d*8+n
  float H = 0.f;
  for(int c = 0; c < NCH; ++c){
    size_t base = ((size_t)br*NCH + c)*2048 + idx;
    float a  = Pa[base];
    float he = Ph[base];
    Ph[base] = H;
    H = he + a*H;
  }
}

// ---------------------------------------------------------------- K8: scan pass 3 (rescan + y)
// NOTE: y_g may alias u_g (per-element read-before-write) -> no restrict on those.
__global__ __launch_bounds__(256) void k_scan3(
    const float* __restrict__ d_g, const float* u_g,
    const float* __restrict__ B_g, const float* __restrict__ C_g,
    const float* __restrict__ Al_s, const float* __restrict__ Al_t,
    const float* __restrict__ D_s, const float* __restrict__ D_t,
    const float* __restrict__ Ph, float* y_g)
{
  const int br = blockIdx.y;
  const int c = blockIdx.x;
  const int d = threadIdx.x;
  const float* dg = d_g + (size_t)br * S_LEN * DI;
  const float* ug = u_g + (size_t)br * S_LEN * DI;
  const float* Bg = B_g + (size_t)br * S_LEN * NS;
  const float* Cg = C_g + (size_t)br * S_LEN * NS;
  const float* Al = br ? Al_t : Al_s;
  const float* Dp = br ? D_t : D_s;
  float* yg = y_g + (size_t)br * S_LEN * DI;
  __shared__ float Bl[CHUNK][NS];
  __shared__ float Cl[CHUNK][NS];
  const int l0 = c * CHUNK;
  for(int i = threadIdx.x; i < CHUNK*NS; i += 256){
    ((float*)Bl)[i] = Bg[(size_t)l0*NS + i];
    ((float*)Cl)[i] = Cg[(size_t)l0*NS + i];
  }
  __syncthreads();
  float A2[NS], h[NS];
  size_t pbase = (((size_t)br*NCH + c)*DI + d) * NS;
  #pragma unroll
  for(int n = 0; n < NS; ++n){
    A2[n] = -__expf(Al[d*NS + n]) * 1.4426950408889634f;
    h[n] = Ph[pbase + n];
  }
  const float Dv = Dp[d];
  for(int l = 0; l < CHUNK; ++l){
    float dl = dg[(size_t)(l0 + l)*DI + d];
    float ul = ug[(size_t)(l0 + l)*DI + d];
    float du = dl * ul;
    float yv = 0.f;
    #pragma unroll
    for(int n = 0; n < NS; ++n){
      float a = exp2f(dl * A2[n]);
      h[n] = a*h[n] + du * Bl[l][n];
      yv += h[n] * Cl[l][n];
    }
    yg[(size_t)(l0 + l)*DI + d] = yv + ul * Dv;
  }
}

// ---------------------------------------------------------------- K9: fused output GEMM
// out[s][m] = sum_d ys[s][d]*Ms[d][m] + sum_d yt[p(s)][d]*Mt[d][m] + sum_ch yc[s][ch]*Mc[ch][m]
__global__ __launch_bounds__(256) void k_out(
    const float* __restrict__ ys, const float* __restrict__ yt, const float* __restrict__ yc,
    const float* __restrict__ Ms, const float* __restrict__ Mt, const float* __restrict__ Mc,
    float* __restrict__ out)
{
  __shared__ float la[FT][DI];
  __shared__ float lb[FT][DI];
  __shared__ float lc[FT][128];
  const int s0 = blockIdx.x * FT;
  const int tid = threadIdx.x;
  for(int i = tid; i < FT*DI; i += 256){
    int r = i >> 8, dd = i & 255;
    int s = s0 + r;
    la[r][dd] = ys[(size_t)s*DI + dd];
    int p = ((s & 1023) << 3) | (s >> 10);
    lb[r][dd] = yt[(size_t)p*DI + dd];
  }
  for(int i = tid; i < FT*128; i += 256){
    int r = i >> 7, cc = i & 127;
    lc[r][cc] = yc[(size_t)(s0 + r)*128 + cc];
  }
  __syncthreads();
  const int m = tid;
  float acc[FT];
  #pragma unroll
  for(int r = 0; r < FT; ++r) acc[r] = 0.f;
  for(int dd = 0; dd < DI; ++dd){
    float w1 = Ms[dd*DI + m];
    float w2 = Mt[dd*DI + m];
    #pragma unroll
    for(int r = 0; r < FT; ++r) acc[r] += w1*la[r][dd] + w2*lb[r][dd];
  }
  for(int cc = 0; cc < 128; ++cc){
    float w = Mc[cc*DI + m];
    #pragma unroll
    for(int r = 0; r < FT; ++r) acc[r] += w*lc[r][cc];
  }
  #pragma unroll
  for(int r = 0; r < FT; ++r)
    out[(size_t)(s0 + r)*DI + m] = acc[r];
}

// ---------------------------------------------------------------- host
extern "C" void kernel_launch(void* const* d_in, const int* in_sizes, int n_in,
                              void* d_out, int out_size, void* d_ws, size_t ws_size,
                              hipStream_t stream)
{
  const float* x      = (const float*)d_in[0];
  const float* inw    = (const float*)d_in[1];
  const float* s_cw   = (const float*)d_in[2];
  const float* s_cb   = (const float*)d_in[3];
  const float* s_xp   = (const float*)d_in[4];
  const float* s_dtw  = (const float*)d_in[5];
  const float* s_dtb  = (const float*)d_in[6];
  const float* s_Al   = (const float*)d_in[7];
  const float* s_D    = (const float*)d_in[8];
  const float* s_ow   = (const float*)d_in[9];
  const float* t_cw   = (const float*)d_in[10];
  const float* t_cb   = (const float*)d_in[11];
  const float* t_xp   = (const float*)d_in[12];
  const float* t_dtw  = (const float*)d_in[13];
  const float* t_dtb  = (const float*)d_in[14];
  const float* t_Al   = (const float*)d_in[15];
  const float* t_D    = (const float*)d_in[16];
  const float* t_ow   = (const float*)d_in[17];
  const float* b_cw   = (const float*)d_in[18];
  const float* b_cb   = (const float*)d_in[19];
  const float* o_w    = (const float*)d_in[20];

  float* ws = (float*)d_ws;
  size_t off = 0;
  auto alloc = [&](size_t n){ float* p = ws + off; off += n; return p; };
  const size_t SD = (size_t)S_LEN * DI;        // 2,097,152
  float* xi_s = alloc(SD);
  float* xi_t = alloc(SD);
  float* u_g  = alloc(2*SD);
  float* d_g  = alloc(2*SD);
  float* B_g  = alloc(2*(size_t)S_LEN*NS);
  float* C_g  = alloc(2*(size_t)S_LEN*NS);
  float* Pa   = alloc(2*(size_t)NCH*DI*NS);
  float* Ph   = alloc(2*(size_t)NCH*DI*NS);
  float* yc   = alloc((size_t)S_LEN*128);
  float* Ms   = alloc((size_t)DI*DI);
  float* Mt   = alloc((size_t)DI*DI);
  float* Mc   = alloc((size_t)128*DI);
  float* y_g  = u_g;                           // ALIAS: scan3 reads u[l][d] before writing y[l][d]
  (void)ws_size; (void)n_in; (void)in_sizes; (void)out_size;

  k_foldw<<<256, 256, 0, stream>>>(s_ow, t_ow, o_w, Ms, Mt, Mc);
  k_inproj<<<S_LEN/K2_ROWS, 256, 0, stream>>>(x, inw, xi_s);
  k_gather_t<<<S_LEN/16, 256, 0, stream>>>(xi_s, xi_t);
  dim3 gprep(S_LEN/PT, 2);
  k_prep<<<gprep, 256, 0, stream>>>(xi_s, xi_t,
      s_cw, s_cb, s_xp, s_dtw, s_dtb,
      t_cw, t_cb, t_xp, t_dtw, t_dtb,
      u_g, d_g, B_g, C_g);
  k_convbranch<<<(S_LEN*128)/256, 256, 0, stream>>>(xi_s, b_cw, b_cb, yc);
  dim3 gscan(NCH, 2);
  k_scan1<<<gscan, 256, 0, stream>>>(d_g, u_g, B_g, s_Al, t_Al, Pa, Ph);
  k_scan2<<<16, 256, 0, stream>>>(Pa, Ph);
  k_scan3<<<gscan, 256, 0, stream>>>(d_g, u_g, B_g, C_g, s_Al, t_Al, s_D, t_D, Ph, y_g);
  k_out<<<S_LEN/FT, 256, 0, stream>>>(y_g, y_g + SD, yc, Ms, Mt, Mc, (float*)d_out);
}

// Round 3
// 157.315 us; speedup vs baseline: 1.7032x; 1.7032x over previous
//
#include <hip/hip_runtime.h>

#define S_LEN 8192
#define DI 256
#define NS 8
#define CHUNK 64
#define NCH 128   // S_LEN / CHUNK
#define PT 32     // positions per prep block

using bf16x8 = __attribute__((ext_vector_type(8))) short;
using f32x4  = __attribute__((ext_vector_type(4))) float;
using u16 = unsigned short;

__device__ __forceinline__ float silu_f(float v){ return v / (1.f + __expf(-v)); }
__device__ __forceinline__ u16 f2b(float f){
  unsigned int u = __float_as_uint(f);
  u += 0x7fffu + ((u >> 16) & 1u);   // RTNE
  return (u16)(u >> 16);
}

// ---------------------------------------------------------------- K0: Wp -> bf16 (Bt layout: [d][c] == Wp row-major)
__global__ __launch_bounds__(256) void k_w2b(const float* __restrict__ Wp, u16* __restrict__ WpB)
{
  const int i = (blockIdx.x * 256 + threadIdx.x) * 4;
  float4 v = *reinterpret_cast<const float4*>(Wp + i);
  WpB[i] = f2b(v.x); WpB[i+1] = f2b(v.y); WpB[i+2] = f2b(v.z); WpB[i+3] = f2b(v.w);
}

// ---------------------------------------------------------------- K1: fold output projections -> MallT bf16 [256 m][640 k]
// k<256:   sum_e Ws[e][k]   * Wo[m][e]
// 256-511: sum_e Wt[e][k-256]* Wo[m][64+e]
// 512-639: Wo[m][128+(k-512)]
__global__ __launch_bounds__(256) void k_foldw(
    const float* __restrict__ Ws, const float* __restrict__ Wt, const float* __restrict__ Wo,
    u16* __restrict__ MallT)
{
  const int m = blockIdx.x;
  const int tid = threadIdx.x;
  // k = tid (space part)
  float as = 0.f, at = 0.f;
  for(int e = 0; e < 64; ++e){
    float we  = Wo[m*DI + e];
    float we2 = Wo[m*DI + 64 + e];
    as += Ws[e*DI + tid] * we;
    at += Wt[e*DI + tid] * we2;
  }
  MallT[(size_t)m*640 + tid]       = f2b(as);
  MallT[(size_t)m*640 + 256 + tid] = f2b(at);
  if(tid < 128)
    MallT[(size_t)m*640 + 512 + tid] = f2b(Wo[m*DI + 128 + tid]);
}

// ---------------------------------------------------------------- MFMA GEMM: C[M][256] = A[M][K] x Bt[256][K]^T
// A: fp32 (converted on the fly) or bf16; Bt bf16; C fp32. BM=BN=BK=64, 4 waves (2x2), wave tile 32x32.
template<int AK, bool A_IS_F32>
__global__ __launch_bounds__(256) void k_gemm(
    const void* __restrict__ Ap, const u16* __restrict__ Bt, float* __restrict__ C)
{
  __shared__ short Al[64][72];
  __shared__ short Bl[64][72];
  const int m0 = blockIdx.x * 64;
  const int n0 = blockIdx.y * 64;
  const int tid = threadIdx.x;
  const int lane = tid & 63;
  const int wave = tid >> 6;
  const int wm = (wave >> 1) * 32;
  const int wn = (wave & 1) * 32;
  f32x4 acc[2][2] = {};
  for(int k0 = 0; k0 < AK; k0 += 64){
    #pragma unroll
    for(int i = 0; i < 2; ++i){
      int idx = tid + 256*i;
      int r = idx >> 3, seg = (idx & 7) * 8;
      if constexpr (A_IS_F32){
        const float* A = (const float*)Ap;
        const float* src = A + (size_t)(m0 + r)*AK + k0 + seg;
        float4 v0 = *reinterpret_cast<const float4*>(src);
        float4 v1 = *reinterpret_cast<const float4*>(src + 4);
        short* dst = &Al[r][seg];
        dst[0]=(short)f2b(v0.x); dst[1]=(short)f2b(v0.y); dst[2]=(short)f2b(v0.z); dst[3]=(short)f2b(v0.w);
        dst[4]=(short)f2b(v1.x); dst[5]=(short)f2b(v1.y); dst[6]=(short)f2b(v1.z); dst[7]=(short)f2b(v1.w);
      } else {
        const u16* A = (const u16*)Ap;
        *reinterpret_cast<bf16x8*>(&Al[r][seg]) =
            *reinterpret_cast<const bf16x8*>(A + (size_t)(m0 + r)*AK + k0 + seg);
      }
      *reinterpret_cast<bf16x8*>(&Bl[r][seg]) =
          *reinterpret_cast<const bf16x8*>(Bt + (size_t)(n0 + r)*AK + k0 + seg);
    }
    __syncthreads();
    #pragma unroll
    for(int kk = 0; kk < 64; kk += 32){
      const int kb = kk + (lane >> 4) * 8;
      bf16x8 a0 = *reinterpret_cast<const bf16x8*>(&Al[wm      + (lane & 15)][kb]);
      bf16x8 a1 = *reinterpret_cast<const bf16x8*>(&Al[wm + 16 + (lane & 15)][kb]);
      bf16x8 b0 = *reinterpret_cast<const bf16x8*>(&Bl[wn      + (lane & 15)][kb]);
      bf16x8 b1 = *reinterpret_cast<const bf16x8*>(&Bl[wn + 16 + (lane & 15)][kb]);
      acc[0][0] = __builtin_amdgcn_mfma_f32_16x16x32_bf16(a0, b0, acc[0][0], 0, 0, 0);
      acc[0][1] = __builtin_amdgcn_mfma_f32_16x16x32_bf16(a0, b1, acc[0][1], 0, 0, 0);
      acc[1][0] = __builtin_amdgcn_mfma_f32_16x16x32_bf16(a1, b0, acc[1][0], 0, 0, 0);
      acc[1][1] = __builtin_amdgcn_mfma_f32_16x16x32_bf16(a1, b1, acc[1][1], 0, 0, 0);
    }
    __syncthreads();
  }
  const int cr = (lane >> 4) * 4, cc = lane & 15;
  #pragma unroll
  for(int fr = 0; fr < 2; ++fr)
    #pragma unroll
    for(int fc = 0; fc < 2; ++fc)
      #pragma unroll
      for(int r = 0; r < 4; ++r)
        C[(size_t)(m0 + wm + fr*16 + cr + r)*DI + n0 + wn + fc*16 + cc] = acc[fr][fc][r];
}

// ---------------------------------------------------------------- K3: gather time-order rows
__global__ __launch_bounds__(256) void k_gather_t(
    const float* __restrict__ xi_s, float* __restrict__ xi_t)
{
  const int p0 = blockIdx.x * 16;
  const int d = threadIdx.x;
  for(int r = 0; r < 16; ++r){
    int p = p0 + r;
    int s = ((p & 7) << 10) | (p >> 3);
    xi_t[(size_t)p*DI + d] = xi_s[(size_t)s*DI + d];
  }
}

// ---------------------------------------------------------------- K4: per-branch prep
__global__ __launch_bounds__(256) void k_prep(
    const float* __restrict__ xi_s, const float* __restrict__ xi_t,
    const float* __restrict__ cw_s, const float* __restrict__ cb_s,
    const float* __restrict__ xp_s, const float* __restrict__ dtw_s, const float* __restrict__ dtb_s,
    const float* __restrict__ cw_t, const float* __restrict__ cb_t,
    const float* __restrict__ xp_t, const float* __restrict__ dtw_t, const float* __restrict__ dtb_t,
    float* __restrict__ u_g, float* __restrict__ d_g,
    float* __restrict__ B_g, float* __restrict__ C_g)
{
  const int br = blockIdx.y;
  const float* X   = br ? xi_t  : xi_s;
  const float* cw  = br ? cw_t  : cw_s;
  const float* cb  = br ? cb_t  : cb_s;
  const float* xpw = br ? xp_t  : xp_s;
  const float* dtw = br ? dtw_t : dtw_s;
  const float* dtb = br ? dtb_t : dtb_s;
  float* ug = u_g + (size_t)br * S_LEN * DI;
  float* dg = d_g + (size_t)br * S_LEN * DI;
  float* Bg = B_g + (size_t)br * S_LEN * NS;
  float* Cg = C_g + (size_t)br * S_LEN * NS;

  __shared__ float xc[PT][DI + 1];
  __shared__ float dbl[32][PT + 1];

  const int tid = threadIdx.x;
  const int l0 = blockIdx.x * PT;

  { // phase A: depthwise conv + silu, thread = d
    const int d = tid;
    float w0 = cw[d*3], w1 = cw[d*3 + 1], w2 = cw[d*3 + 2];
    float bb = cb[d];
    float xm = (l0 > 0) ? X[(size_t)(l0 - 1)*DI + d] : 0.f;
    float x0 = X[(size_t)l0*DI + d];
    for(int pos = 0; pos < PT; ++pos){
      int l = l0 + pos;
      float xp = (l + 1 < S_LEN) ? X[(size_t)(l + 1)*DI + d] : 0.f;
      float v = w0*xm + w1*x0 + w2*xp + bb;
      float xcv = silu_f(v);
      ug[(size_t)l*DI + d] = xcv;
      xc[pos][d] = xcv;
      xm = x0; x0 = xp;
    }
  }
  __syncthreads();
  { // phase B
    const int pos = tid & 31;
    const int e0 = tid >> 5;
    float a0 = 0.f, a1 = 0.f, a2 = 0.f, a3 = 0.f;
    for(int d = 0; d < DI; ++d){
      float xv = xc[pos][d];
      a0 += xpw[(e0      )*DI + d] * xv;
      a1 += xpw[(e0 +  8 )*DI + d] * xv;
      a2 += xpw[(e0 + 16 )*DI + d] * xv;
      a3 += xpw[(e0 + 24 )*DI + d] * xv;
    }
    dbl[e0     ][pos] = a0;
    dbl[e0 +  8][pos] = a1;
    dbl[e0 + 16][pos] = a2;
    dbl[e0 + 24][pos] = a3;
  }
  __syncthreads();
  { // write B/C
    const int pos = tid >> 3;
    const int n = tid & 7;
    Bg[(size_t)(l0 + pos)*NS + n] = dbl[16 + n][pos];
    Cg[(size_t)(l0 + pos)*NS + n] = dbl[24 + n][pos];
  }
  { // phase C: delta
    const int d = tid;
    float dw[16];
    #pragma unroll
    for(int r = 0; r < 16; ++r) dw[r] = dtw[d*16 + r];
    const float b2 = 2.f * dtb[d];
    for(int pos = 0; pos < PT; ++pos){
      float a = b2;
      #pragma unroll
      for(int r = 0; r < 16; ++r) a += dw[r] * dbl[r][pos];
      float dlt = (a > 15.f) ? a : log1pf(__expf(a));
      dg[(size_t)(l0 + pos)*DI + d] = dlt;
    }
  }
}

// ---------------------------------------------------------------- K5: grouped conv branch -> Yb cols 512..639
__global__ __launch_bounds__(256) void k_convbranch(
    const float* __restrict__ xi_s, const float* __restrict__ bw, const float* __restrict__ bb,
    u16* __restrict__ Yb)
{
  const int t = blockIdx.x * 256 + threadIdx.x;
  const int ch = t & 127;
  const int s = t >> 7;
  float acc = bb[ch];
  #pragma unroll
  for(int k = 0; k < 3; ++k){
    int l = s + k - 1;
    if(l >= 0 && l < S_LEN){
      acc += bw[ch*6 + k]     * xi_s[(size_t)l*DI + 2*ch];
      acc += bw[ch*6 + 3 + k] * xi_s[(size_t)l*DI + 2*ch + 1];
    }
  }
  Yb[(size_t)s*640 + 512 + ch] = f2b(silu_f(acc));
}

// ---------------------------------------------------------------- K6: scan pass 1
__global__ __launch_bounds__(256) void k_scan1(
    const float* __restrict__ d_g, const float* __restrict__ u_g,
    const float* __restrict__ B_g,
    const float* __restrict__ Al_s, const float* __restrict__ Al_t,
    float* __restrict__ Pa, float* __restrict__ Ph)
{
  const int br = blockIdx.y;
  const int c = blockIdx.x;
  const int d = threadIdx.x;
  const float* dg = d_g + (size_t)br * S_LEN * DI;
  const float* ug = u_g + (size_t)br * S_LEN * DI;
  const float* Bg = B_g + (size_t)br * S_LEN * NS;
  const float* Al = br ? Al_t : Al_s;
  __shared__ float Bl[CHUNK][NS];
  const int l0 = c * CHUNK;
  for(int i = threadIdx.x; i < CHUNK*NS; i += 256)
    ((float*)Bl)[i] = Bg[(size_t)l0*NS + i];
  __syncthreads();
  float A2[NS], h[NS], ap[NS];
  #pragma unroll
  for(int n = 0; n < NS; ++n){
    A2[n] = -__expf(Al[d*NS + n]) * 1.4426950408889634f;
    h[n] = 0.f; ap[n] = 1.f;
  }
  for(int l = 0; l < CHUNK; ++l){
    float dl = dg[(size_t)(l0 + l)*DI + d];
    float du = dl * ug[(size_t)(l0 + l)*DI + d];
    #pragma unroll
    for(int n = 0; n < NS; ++n){
      float a = exp2f(dl * A2[n]);
      ap[n] *= a;
      h[n] = a*h[n] + du * Bl[l][n];
    }
  }
  size_t base = (((size_t)br*NCH + c)*DI + d) * NS;
  #pragma unroll
  for(int n = 0; n < NS; ++n){ Pa[base + n] = ap[n]; Ph[base + n] = h[n]; }
}

// ---------------------------------------------------------------- K7: scan pass 2 (combine)
__global__ __launch_bounds__(256) void k_scan2(
    const float* __restrict__ Pa, float* __restrict__ Ph)
{
  const int t = blockIdx.x * 256 + threadIdx.x;  // 4096 total
  const int br = t >> 11;
  const int idx = t & 2047;
  float H = 0.f;
  for(int c = 0; c < NCH; ++c){
    size_t base = ((size_t)br*NCH + c)*2048 + idx;
    float a  = Pa[base];
    float he = Ph[base];
    Ph[base] = H;
    H = he + a*H;
  }
}

// ---------------------------------------------------------------- K8: scan pass 3 -> Yb (bf16, gathered layout)
__global__ __launch_bounds__(256) void k_scan3(
    const float* __restrict__ d_g, const float* __restrict__ u_g,
    const float* __restrict__ B_g, const float* __restrict__ C_g,
    const float* __restrict__ Al_s, const float* __restrict__ Al_t,
    const float* __restrict__ D_s, const float* __restrict__ D_t,
    const float* __restrict__ Ph, u16* __restrict__ Yb)
{
  const int br = blockIdx.y;
  const int c = blockIdx.x;
  const int d = threadIdx.x;
  const float* dg = d_g + (size_t)br * S_LEN * DI;
  const float* ug = u_g + (size_t)br * S_LEN * DI;
  const float* Bg = B_g + (size_t)br * S_LEN * NS;
  const float* Cg = C_g + (size_t)br * S_LEN * NS;
  const float* Al = br ? Al_t : Al_s;
  const float* Dp = br ? D_t : D_s;
  __shared__ float Bl[CHUNK][NS];
  __shared__ float Cl[CHUNK][NS];
  const int l0 = c * CHUNK;
  for(int i = threadIdx.x; i < CHUNK*NS; i += 256){
    ((float*)Bl)[i] = Bg[(size_t)l0*NS + i];
    ((float*)Cl)[i] = Cg[(size_t)l0*NS + i];
  }
  __syncthreads();
  float A2[NS], h[NS];
  size_t pbase = (((size_t)br*NCH + c)*DI + d) * NS;
  #pragma unroll
  for(int n = 0; n < NS; ++n){
    A2[n] = -__expf(Al[d*NS + n]) * 1.4426950408889634f;
    h[n] = Ph[pbase + n];
  }
  const float Dv = Dp[d];
  for(int l = 0; l < CHUNK; ++l){
    int p = l0 + l;
    float dl = dg[(size_t)p*DI + d];
    float ul = ug[(size_t)p*DI + d];
    float du = dl * ul;
    float yv = 0.f;
    #pragma unroll
    for(int n = 0; n < NS; ++n){
      float a = exp2f(dl * A2[n]);
      h[n] = a*h[n] + du * Bl[l][n];
      yv += h[n] * Cl[l][n];
    }
    float out = yv + ul * Dv;
    if(br == 0){
      Yb[(size_t)p*640 + d] = f2b(out);
    } else {
      int sp = ((p & 7) << 10) | (p >> 3);   // row that consumes time-position p
      Yb[(size_t)sp*640 + 256 + d] = f2b(out);
    }
  }
}

// ---------------------------------------------------------------- host
extern "C" void kernel_launch(void* const* d_in, const int* in_sizes, int n_in,
                              void* d_out, int out_size, void* d_ws, size_t ws_size,
                              hipStream_t stream)
{
  const float* x      = (const float*)d_in[0];
  const float* inw    = (const float*)d_in[1];
  const float* s_cw   = (const float*)d_in[2];
  const float* s_cb   = (const float*)d_in[3];
  const float* s_xp   = (const float*)d_in[4];
  const float* s_dtw  = (const float*)d_in[5];
  const float* s_dtb  = (const float*)d_in[6];
  const float* s_Al   = (const float*)d_in[7];
  const float* s_D    = (const float*)d_in[8];
  const float* s_ow   = (const float*)d_in[9];
  const float* t_cw   = (const float*)d_in[10];
  const float* t_cb   = (const float*)d_in[11];
  const float* t_xp   = (const float*)d_in[12];
  const float* t_dtw  = (const float*)d_in[13];
  const float* t_dtb  = (const float*)d_in[14];
  const float* t_Al   = (const float*)d_in[15];
  const float* t_D    = (const float*)d_in[16];
  const float* t_ow   = (const float*)d_in[17];
  const float* b_cw   = (const float*)d_in[18];
  const float* b_cb   = (const float*)d_in[19];
  const float* o_w    = (const float*)d_in[20];

  float* ws = (float*)d_ws;
  size_t off = 0;
  auto alloc = [&](size_t n){ float* p = ws + off; off += n; return p; };
  const size_t SD = (size_t)S_LEN * DI;        // 2,097,152
  float* xi_s = alloc(SD);
  float* xi_t = alloc(SD);
  float* u_g  = alloc(2*SD);
  float* d_g  = alloc(2*SD);
  float* B_g  = alloc(2*(size_t)S_LEN*NS);
  float* C_g  = alloc(2*(size_t)S_LEN*NS);
  float* Pa   = alloc(2*(size_t)NCH*DI*NS);
  float* Ph   = alloc(2*(size_t)NCH*DI*NS);
  u16*   Yb   = (u16*)alloc((size_t)S_LEN*640/2);   // 8192x640 bf16
  u16*   WpB  = (u16*)alloc((size_t)DI*DI/2);
  u16*   MallT= (u16*)alloc((size_t)DI*640/2);
  (void)ws_size; (void)n_in; (void)in_sizes; (void)out_size;

  k_w2b<<<DI*DI/(256*4), 256, 0, stream>>>(inw, WpB);
  k_foldw<<<256, 256, 0, stream>>>(s_ow, t_ow, o_w, MallT);

  dim3 ggemm(S_LEN/64, DI/64);
  k_gemm<DI, true><<<ggemm, 256, 0, stream>>>(x, WpB, xi_s);

  k_gather_t<<<S_LEN/16, 256, 0, stream>>>(xi_s, xi_t);
  dim3 gprep(S_LEN/PT, 2);
  k_prep<<<gprep, 256, 0, stream>>>(xi_s, xi_t,
      s_cw, s_cb, s_xp, s_dtw, s_dtb,
      t_cw, t_cb, t_xp, t_dtw, t_dtb,
      u_g, d_g, B_g, C_g);
  k_convbranch<<<(S_LEN*128)/256, 256, 0, stream>>>(xi_s, b_cw, b_cb, Yb);
  dim3 gscan(NCH, 2);
  k_scan1<<<gscan, 256, 0, stream>>>(d_g, u_g, B_g, s_Al, t_Al, Pa, Ph);
  k_scan2<<<16, 256, 0, stream>>>(Pa, Ph);
  k_scan3<<<gscan, 256, 0, stream>>>(d_g, u_g, B_g, C_g, s_Al, t_Al, s_D, t_D, Ph, Yb);

  k_gemm<640, false><<<ggemm, 256, 0, stream>>>(Yb, MallT, (float*)d_out);
}

// Round 4
// 114.018 us; speedup vs baseline: 2.3499x; 1.3797x over previous
//
#include <hip/hip_runtime.h>

#define S_LEN 8192
#define DI 256
#define NS 8
#define CHUNK 32
#define NCH 256   // S_LEN / CHUNK
#define PT 32     // positions per prep block (== CHUNK)

using bf16x8 = __attribute__((ext_vector_type(8))) short;
using f32x4  = __attribute__((ext_vector_type(4))) float;
using u16 = unsigned short;

#define LOG2E 1.4426950408889634f
#define LN2   0.6931471805599453f

__device__ __forceinline__ float silu_f(float v){ return v / (1.f + __expf(-v)); }
__device__ __forceinline__ u16 f2b(float f){
  unsigned int u = __float_as_uint(f);
  u += 0x7fffu + ((u >> 16) & 1u);   // RTNE
  return (u16)(u >> 16);
}

// ---------------------------------------------------------------- K0: f32 -> bf16 (row-major copy)
__global__ __launch_bounds__(256) void k_w2b(const float* __restrict__ src, u16* __restrict__ dst)
{
  const int i = (blockIdx.x * 256 + threadIdx.x) * 4;
  float4 v = *reinterpret_cast<const float4*>(src + i);
  dst[i] = f2b(v.x); dst[i+1] = f2b(v.y); dst[i+2] = f2b(v.z); dst[i+3] = f2b(v.w);
}

// ---------------------------------------------------------------- K1: fold output projections -> MallT bf16 [256 m][640 k]
__global__ __launch_bounds__(256) void k_foldw(
    const float* __restrict__ Ws, const float* __restrict__ Wt, const float* __restrict__ Wo,
    u16* __restrict__ MallT)
{
  const int m = blockIdx.x;
  const int tid = threadIdx.x;
  float as = 0.f, at = 0.f;
  for(int e = 0; e < 64; ++e){
    as += Ws[e*DI + tid] * Wo[m*DI + e];
    at += Wt[e*DI + tid] * Wo[m*DI + 64 + e];
  }
  MallT[(size_t)m*640 + tid]       = f2b(as);
  MallT[(size_t)m*640 + 256 + tid] = f2b(at);
  if(tid < 128)
    MallT[(size_t)m*640 + 512 + tid] = f2b(Wo[m*DI + 128 + tid]);
}

// ---------------------------------------------------------------- MFMA GEMM: C[M][256] = A[M][K] x Bt[256][K]^T
template<int AK, bool A_IS_F32>
__global__ __launch_bounds__(256) void k_gemm(
    const void* __restrict__ Ap, const u16* __restrict__ Bt, float* __restrict__ C)
{
  __shared__ short Al[64][72];
  __shared__ short Bl[64][72];
  const int m0 = blockIdx.x * 64;
  const int n0 = blockIdx.y * 64;
  const int tid = threadIdx.x;
  const int lane = tid & 63;
  const int wave = tid >> 6;
  const int wm = (wave >> 1) * 32;
  const int wn = (wave & 1) * 32;
  f32x4 acc[2][2] = {};
  for(int k0 = 0; k0 < AK; k0 += 64){
    #pragma unroll
    for(int i = 0; i < 2; ++i){
      int idx = tid + 256*i;
      int r = idx >> 3, seg = (idx & 7) * 8;
      if constexpr (A_IS_F32){
        const float* A = (const float*)Ap;
        const float* src = A + (size_t)(m0 + r)*AK + k0 + seg;
        float4 v0 = *reinterpret_cast<const float4*>(src);
        float4 v1 = *reinterpret_cast<const float4*>(src + 4);
        short* dst = &Al[r][seg];
        dst[0]=(short)f2b(v0.x); dst[1]=(short)f2b(v0.y); dst[2]=(short)f2b(v0.z); dst[3]=(short)f2b(v0.w);
        dst[4]=(short)f2b(v1.x); dst[5]=(short)f2b(v1.y); dst[6]=(short)f2b(v1.z); dst[7]=(short)f2b(v1.w);
      } else {
        const u16* A = (const u16*)Ap;
        *reinterpret_cast<bf16x8*>(&Al[r][seg]) =
            *reinterpret_cast<const bf16x8*>(A + (size_t)(m0 + r)*AK + k0 + seg);
      }
      *reinterpret_cast<bf16x8*>(&Bl[r][seg]) =
          *reinterpret_cast<const bf16x8*>(Bt + (size_t)(n0 + r)*AK + k0 + seg);
    }
    __syncthreads();
    #pragma unroll
    for(int kk = 0; kk < 64; kk += 32){
      const int kb = kk + (lane >> 4) * 8;
      bf16x8 a0 = *reinterpret_cast<const bf16x8*>(&Al[wm      + (lane & 15)][kb]);
      bf16x8 a1 = *reinterpret_cast<const bf16x8*>(&Al[wm + 16 + (lane & 15)][kb]);
      bf16x8 b0 = *reinterpret_cast<const bf16x8*>(&Bl[wn      + (lane & 15)][kb]);
      bf16x8 b1 = *reinterpret_cast<const bf16x8*>(&Bl[wn + 16 + (lane & 15)][kb]);
      acc[0][0] = __builtin_amdgcn_mfma_f32_16x16x32_bf16(a0, b0, acc[0][0], 0, 0, 0);
      acc[0][1] = __builtin_amdgcn_mfma_f32_16x16x32_bf16(a0, b1, acc[0][1], 0, 0, 0);
      acc[1][0] = __builtin_amdgcn_mfma_f32_16x16x32_bf16(a1, b0, acc[1][0], 0, 0, 0);
      acc[1][1] = __builtin_amdgcn_mfma_f32_16x16x32_bf16(a1, b1, acc[1][1], 0, 0, 0);
    }
    __syncthreads();
  }
  const int cr = (lane >> 4) * 4, cc = lane & 15;
  #pragma unroll
  for(int fr = 0; fr < 2; ++fr)
    #pragma unroll
    for(int fc = 0; fc < 2; ++fc)
      #pragma unroll
      for(int r = 0; r < 4; ++r)
        C[(size_t)(m0 + wm + fr*16 + cr + r)*DI + n0 + wn + fc*16 + cc] = acc[fr][fc][r];
}

// ---------------------------------------------------------------- K4: per-branch prep + local scan (pass 1)
// phase A: xc = silu(dwconv(X)) (direct-gather rows for time branch)
// phase B: dbl[32e][32pos] = xpw @ xc^T via MFMA
// phase C: delta = softplus(dtw@dtp + 2*dtb); fused chunk-local scan -> Pa, Ph
__global__ __launch_bounds__(256) void k_prep(
    const float* __restrict__ xi,
    const float* __restrict__ cw_s, const float* __restrict__ cb_s,
    const u16* __restrict__ xpB_s, const float* __restrict__ dtw_s, const float* __restrict__ dtb_s,
    const float* __restrict__ Al_s,
    const float* __restrict__ cw_t, const float* __restrict__ cb_t,
    const u16* __restrict__ xpB_t, const float* __restrict__ dtw_t, const float* __restrict__ dtb_t,
    const float* __restrict__ Al_t,
    float* __restrict__ u_g, float* __restrict__ d_g,
    float* __restrict__ B_g, float* __restrict__ C_g,
    float* __restrict__ Pa, float* __restrict__ Ph)
{
  const int br = blockIdx.y;
  const float* cw  = br ? cw_t  : cw_s;
  const float* cb  = br ? cb_t  : cb_s;
  const u16*  xpB  = br ? xpB_t : xpB_s;
  const float* dtw = br ? dtw_t : dtw_s;
  const float* dtb = br ? dtb_t : dtb_s;
  const float* Al  = br ? Al_t  : Al_s;
  float* ug = u_g + (size_t)br * S_LEN * DI;
  float* dg = d_g + (size_t)br * S_LEN * DI;
  float* Bg = B_g + (size_t)br * S_LEN * NS;
  float* Cg = C_g + (size_t)br * S_LEN * NS;

  __shared__ float xcf[PT][DI + 1];   // fp32 xc (for fused scan u)
  __shared__ u16   xcB[PT][264];      // bf16 xc (MFMA B operand)
  __shared__ float dbl[32][33];       // e x pos

  const int tid = threadIdx.x;
  const int l0 = blockIdx.x * PT;

  { // phase A: depthwise conv + silu, thread = d
    const int d = tid;
    float w0 = cw[d*3], w1 = cw[d*3 + 1], w2 = cw[d*3 + 2];
    float bb = cb[d];
    auto rowv = [&](int l)->float{
      if(l < 0 || l >= S_LEN) return 0.f;
      int s = br ? (((l & 7) << 10) | (l >> 3)) : l;
      return xi[(size_t)s*DI + d];
    };
    float xm = rowv(l0 - 1);
    float x0 = rowv(l0);
    for(int pos = 0; pos < PT; ++pos){
      int l = l0 + pos;
      float xp = rowv(l + 1);
      float v = w0*xm + w1*x0 + w2*xp + bb;
      float xcv = silu_f(v);
      ug[(size_t)l*DI + d] = xcv;
      xcf[pos][d] = xcv;
      xcB[pos][d] = f2b(xcv);
      xm = x0; x0 = xp;
    }
  }
  __syncthreads();
  { // phase B: 4 waves, one 16x16 tile each: dbl[e0..e0+16][p0..p0+16]
    const int lane = tid & 63;
    const int wave = tid >> 6;
    const int e0 = (wave >> 1) * 16;
    const int p0 = (wave & 1) * 16;
    f32x4 acc = {};
    #pragma unroll
    for(int kk = 0; kk < DI; kk += 32){
      const int kb = kk + (lane >> 4) * 8;
      bf16x8 a = *reinterpret_cast<const bf16x8*>(xpB + (size_t)(e0 + (lane & 15))*DI + kb);
      bf16x8 b = *reinterpret_cast<const bf16x8*>(&xcB[p0 + (lane & 15)][kb]);
      acc = __builtin_amdgcn_mfma_f32_16x16x32_bf16(a, b, acc, 0, 0, 0);
    }
    const int cr = (lane >> 4) * 4, cc = lane & 15;
    #pragma unroll
    for(int r = 0; r < 4; ++r)
      dbl[e0 + cr + r][p0 + cc] = acc[r];
  }
  __syncthreads();
  { // write B (rows 16..23) and C (rows 24..31) to global for scan3
    const int pos = tid >> 3;
    const int n = tid & 7;
    Bg[(size_t)(l0 + pos)*NS + n] = dbl[16 + n][pos];
    Cg[(size_t)(l0 + pos)*NS + n] = dbl[24 + n][pos];
  }
  { // phase C: delta + fused chunk-local scan (pass 1)
    const int d = tid;
    float dw[16];
    const float4* dtw4 = reinterpret_cast<const float4*>(dtw + d*16);
    #pragma unroll
    for(int q = 0; q < 4; ++q){
      float4 v = dtw4[q];
      dw[q*4] = v.x; dw[q*4+1] = v.y; dw[q*4+2] = v.z; dw[q*4+3] = v.w;
    }
    const float b2 = 2.f * dtb[d];
    float A2[NS], h[NS], ap[NS];
    #pragma unroll
    for(int n = 0; n < NS; ++n){
      A2[n] = -__expf(Al[d*NS + n]) * LOG2E;
      h[n] = 0.f; ap[n] = 1.f;
    }
    for(int pos = 0; pos < PT; ++pos){
      float a = b2;
      #pragma unroll
      for(int r = 0; r < 16; ++r) a += dw[r] * dbl[r][pos];
      float dlt = (a > 15.f) ? a : LN2 * __log2f(1.f + exp2f(a * LOG2E));
      dg[(size_t)(l0 + pos)*DI + d] = dlt;
      float du = dlt * xcf[pos][d];
      #pragma unroll
      for(int n = 0; n < NS; ++n){
        float e = exp2f(dlt * A2[n]);
        ap[n] *= e;
        h[n] = e*h[n] + du * dbl[16 + n][pos];
      }
    }
    size_t base = (((size_t)br*NCH + blockIdx.x)*DI + d) * NS;
    #pragma unroll
    for(int n = 0; n < NS; ++n){ Pa[base + n] = ap[n]; Ph[base + n] = h[n]; }
  }
}

// ---------------------------------------------------------------- K5: grouped conv branch -> Yb cols 512..639
__global__ __launch_bounds__(256) void k_convbranch(
    const float* __restrict__ xi_s, const float* __restrict__ bw, const float* __restrict__ bb,
    u16* __restrict__ Yb)
{
  const int t = blockIdx.x * 256 + threadIdx.x;
  const int ch = t & 127;
  const int s = t >> 7;
  float acc = bb[ch];
  #pragma unroll
  for(int k = 0; k < 3; ++k){
    int l = s + k - 1;
    if(l >= 0 && l < S_LEN){
      acc += bw[ch*6 + k]     * xi_s[(size_t)l*DI + 2*ch];
      acc += bw[ch*6 + 3 + k] * xi_s[(size_t)l*DI + 2*ch + 1];
    }
  }
  Yb[(size_t)s*640 + 512 + ch] = f2b(silu_f(acc));
}

// ---------------------------------------------------------------- K7: scan pass 2 (combine)
__global__ __launch_bounds__(256) void k_scan2(
    const float* __restrict__ Pa, float* __restrict__ Ph)
{
  const int t = blockIdx.x * 256 + threadIdx.x;  // 4096 total
  const int br = t >> 11;
  const int idx = t & 2047;
  float H = 0.f;
  for(int c = 0; c < NCH; ++c){
    size_t base = ((size_t)br*NCH + c)*2048 + idx;
    float a  = Pa[base];
    float he = Ph[base];
    Ph[base] = H;
    H = he + a*H;
  }
}

// ---------------------------------------------------------------- K8: scan pass 3 -> Yb (bf16, gathered layout)
__global__ __launch_bounds__(256) void k_scan3(
    const float* __restrict__ d_g, const float* __restrict__ u_g,
    const float* __restrict__ B_g, const float* __restrict__ C_g,
    const float* __restrict__ Al_s, const float* __restrict__ Al_t,
    const float* __restrict__ D_s, const float* __restrict__ D_t,
    const float* __restrict__ Ph, u16* __restrict__ Yb)
{
  const int br = blockIdx.y;
  const int c = blockIdx.x;
  const int d = threadIdx.x;
  const float* dg = d_g + (size_t)br * S_LEN * DI;
  const float* ug = u_g + (size_t)br * S_LEN * DI;
  const float* Bg = B_g + (size_t)br * S_LEN * NS;
  const float* Cg = C_g + (size_t)br * S_LEN * NS;
  const float* Al = br ? Al_t : Al_s;
  const float* Dp = br ? D_t : D_s;
  __shared__ float Bl[CHUNK][NS];
  __shared__ float Cl[CHUNK][NS];
  const int l0 = c * CHUNK;
  for(int i = threadIdx.x; i < CHUNK*NS; i += 256){
    ((float*)Bl)[i] = Bg[(size_t)l0*NS + i];
    ((float*)Cl)[i] = Cg[(size_t)l0*NS + i];
  }
  __syncthreads();
  float A2[NS], h[NS];
  size_t pbase = (((size_t)br*NCH + c)*DI + d) * NS;
  #pragma unroll
  for(int n = 0; n < NS; ++n){
    A2[n] = -__expf(Al[d*NS + n]) * LOG2E;
    h[n] = Ph[pbase + n];
  }
  const float Dv = Dp[d];
  for(int l = 0; l < CHUNK; ++l){
    int p = l0 + l;
    float dl = dg[(size_t)p*DI + d];
    float ul = ug[(size_t)p*DI + d];
    float du = dl * ul;
    float yv = 0.f;
    #pragma unroll
    for(int n = 0; n < NS; ++n){
      float a = exp2f(dl * A2[n]);
      h[n] = a*h[n] + du * Bl[l][n];
      yv += h[n] * Cl[l][n];
    }
    float out = yv + ul * Dv;
    if(br == 0){
      Yb[(size_t)p*640 + d] = f2b(out);
    } else {
      int sp = ((p & 7) << 10) | (p >> 3);
      Yb[(size_t)sp*640 + 256 + d] = f2b(out);
    }
  }
}

// ---------------------------------------------------------------- host
extern "C" void kernel_launch(void* const* d_in, const int* in_sizes, int n_in,
                              void* d_out, int out_size, void* d_ws, size_t ws_size,
                              hipStream_t stream)
{
  const float* x      = (const float*)d_in[0];
  const float* inw    = (const float*)d_in[1];
  const float* s_cw   = (const float*)d_in[2];
  const float* s_cb   = (const float*)d_in[3];
  const float* s_xp   = (const float*)d_in[4];
  const float* s_dtw  = (const float*)d_in[5];
  const float* s_dtb  = (const float*)d_in[6];
  const float* s_Al   = (const float*)d_in[7];
  const float* s_D    = (const float*)d_in[8];
  const float* s_ow   = (const float*)d_in[9];
  const float* t_cw   = (const float*)d_in[10];
  const float* t_cb   = (const float*)d_in[11];
  const float* t_xp   = (const float*)d_in[12];
  const float* t_dtw  = (const float*)d_in[13];
  const float* t_dtb  = (const float*)d_in[14];
  const float* t_Al   = (const float*)d_in[15];
  const float* t_D    = (const float*)d_in[16];
  const float* t_ow   = (const float*)d_in[17];
  const float* b_cw   = (const float*)d_in[18];
  const float* b_cb   = (const float*)d_in[19];
  const float* o_w    = (const float*)d_in[20];

  float* ws = (float*)d_ws;
  size_t off = 0;
  auto alloc = [&](size_t n){ float* p = ws + off; off += n; return p; };
  const size_t SD = (size_t)S_LEN * DI;        // 2,097,152
  float* xi_s = alloc(SD);
  float* u_g  = alloc(2*SD);
  float* d_g  = alloc(2*SD);
  float* B_g  = alloc(2*(size_t)S_LEN*NS);
  float* C_g  = alloc(2*(size_t)S_LEN*NS);
  float* Pa   = alloc(2*(size_t)NCH*DI*NS);
  float* Ph   = alloc(2*(size_t)NCH*DI*NS);
  u16*   Yb   = (u16*)alloc((size_t)S_LEN*640/2);   // 8192x640 bf16
  u16*   WpB  = (u16*)alloc((size_t)DI*DI/2);
  u16*   MallT= (u16*)alloc((size_t)DI*640/2);
  u16*   xpB_s= (u16*)alloc((size_t)32*DI/2);
  u16*   xpB_t= (u16*)alloc((size_t)32*DI/2);
  (void)ws_size; (void)n_in; (void)in_sizes; (void)out_size;

  k_w2b<<<DI*DI/1024, 256, 0, stream>>>(inw, WpB);
  k_w2b<<<32*DI/1024, 256, 0, stream>>>(s_xp, xpB_s);
  k_w2b<<<32*DI/1024, 256, 0, stream>>>(t_xp, xpB_t);
  k_foldw<<<256, 256, 0, stream>>>(s_ow, t_ow, o_w, MallT);

  dim3 ggemm(S_LEN/64, DI/64);
  k_gemm<DI, true><<<ggemm, 256, 0, stream>>>(x, WpB, xi_s);

  dim3 gprep(S_LEN/PT, 2);
  k_prep<<<gprep, 256, 0, stream>>>(xi_s,
      s_cw, s_cb, xpB_s, s_dtw, s_dtb, s_Al,
      t_cw, t_cb, xpB_t, t_dtw, t_dtb, t_Al,
      u_g, d_g, B_g, C_g, Pa, Ph);
  k_convbranch<<<(S_LEN*128)/256, 256, 0, stream>>>(xi_s, b_cw, b_cb, Yb);
  k_scan2<<<16, 256, 0, stream>>>(Pa, Ph);
  dim3 gscan(NCH, 2);
  k_scan3<<<gscan, 256, 0, stream>>>(d_g, u_g, B_g, C_g, s_Al, t_Al, s_D, t_D, Ph, Yb);

  k_gemm<640, false><<<ggemm, 256, 0, stream>>>(Yb, MallT, (float*)d_out);
}